// Round 1
// baseline (299.980 us; speedup 1.0000x reference)
//
#include <hip/hip_runtime.h>
#include <stdint.h>

typedef __bf16 bf16;
typedef __bf16 bf16x4 __attribute__((ext_vector_type(4)));
typedef __bf16 bf16x8 __attribute__((ext_vector_type(8)));
typedef short short4v __attribute__((ext_vector_type(4)));
typedef float floatx4 __attribute__((ext_vector_type(4)));

#define MFMA32(a, b, c) __builtin_amdgcn_mfma_f32_16x16x32_bf16((a), (b), (c), 0, 0, 0)

__device__ __forceinline__ floatx4 mfma16(bf16x4 a, bf16x4 b, floatx4 c) {
  return __builtin_amdgcn_mfma_f32_16x16x16bf16_1k(
      __builtin_bit_cast(short4v, a), __builtin_bit_cast(short4v, b), c, 0, 0, 0);
}

__device__ __forceinline__ void gload16(const void* g, void* l) {
  __builtin_amdgcn_global_load_lds(
      (const __attribute__((address_space(1))) void*)g,
      (__attribute__((address_space(3))) void*)l, 16, 0, 0);
}

__device__ __forceinline__ bf16x8 load8(const float* p) {
  float4 lo = *(const float4*)p;
  float4 hi = *(const float4*)(p + 4);
  bf16x8 r;
  r[0] = (bf16)lo.x; r[1] = (bf16)lo.y; r[2] = (bf16)lo.z; r[3] = (bf16)lo.w;
  r[4] = (bf16)hi.x; r[5] = (bf16)hi.y; r[6] = (bf16)hi.z; r[7] = (bf16)hi.w;
  return r;
}

// One launch converting x, Wq, Wo to bf16. grid (2048, 3), 8 elems/thread.
__global__ __launch_bounds__(256) void conv3(const float* __restrict__ a, bf16* __restrict__ ab,
                                             const float* __restrict__ b, bf16* __restrict__ bb,
                                             const float* __restrict__ c, bf16* __restrict__ cb) {
  const int i = blockIdx.x * 256 + threadIdx.x;
  const float* src = blockIdx.y == 0 ? a : (blockIdx.y == 1 ? b : c);
  bf16* dst = blockIdx.y == 0 ? ab : (blockIdx.y == 1 ? bb : cb);
  ((bf16x8*)dst)[i] = load8(src + (size_t)i * 8);
}

// Pack K (f32->bf16) and transpose-pack V: Vf[t][64] -> Vtb[d][2048].
__global__ __launch_bounds__(256) void pack_kv(const float* __restrict__ Kf,
                                               const float* __restrict__ Vf,
                                               bf16* __restrict__ Kb,
                                               bf16* __restrict__ Vtb) {
  int i = blockIdx.x * 256 + threadIdx.x;
  if (i < 2048 * 64) {
    Kb[i] = (bf16)Kf[i];
    const int t = i >> 6, d = i & 63;
    Vtb[(size_t)d * 2048 + t] = (bf16)Vf[i];
  }
}

// C[M,N] = A[M,K] @ B[N,K]^T, bf16 in, dbuf global_load_lds staging.
// 64x128 C-tile -> 512 blocks = 2 blocks/CU co-resident (R6 validated).
template <typename TC>
__global__ __launch_bounds__(256) void gemm_bt_a(const bf16* __restrict__ A,
                                                 const bf16* __restrict__ B,
                                                 TC* __restrict__ C,
                                                 int M, int N, int K) {
  __shared__ __align__(16) bf16 As[2][64 * 32];
  __shared__ __align__(16) bf16 Bs[2][128 * 32];
  const int tid = threadIdx.x;
  const int wave = tid >> 6, lane = tid & 63;
  const int quad = lane >> 4, l16 = lane & 15;
  const int m0 = blockIdx.y * 64, n0 = blockIdx.x * 128;
  const int wm = (wave >> 1) * 32, wn = (wave & 1) * 64;

  floatx4 acc[2][4];
#pragma unroll
  for (int i = 0; i < 2; i++)
#pragma unroll
    for (int j = 0; j < 4; j++) acc[i][j] = (floatx4)0.f;

  const int srow = tid >> 2, scol = (tid & 3) * 8;
  const bf16* Ap = A + (size_t)(m0 + srow) * K + scol;
  const bf16* Bp = B + (size_t)(n0 + srow) * K + scol;

  auto stage = [&](int k0, int buf) {
    gload16(Ap + k0, (char*)As[buf] + tid * 16);
    gload16(Bp + k0, (char*)Bs[buf] + tid * 16);
    gload16(Bp + (size_t)64 * K + k0, (char*)Bs[buf] + 4096 + tid * 16);
  };
  auto compute = [&](int buf) {
    bf16x8 af[2], bfr[4];
#pragma unroll
    for (int mt = 0; mt < 2; mt++)
      af[mt] = *(const bf16x8*)(&As[buf][(wm + mt * 16 + l16) * 32 + quad * 8]);
#pragma unroll
    for (int nt = 0; nt < 4; nt++)
      bfr[nt] = *(const bf16x8*)(&Bs[buf][(wn + nt * 16 + l16) * 32 + quad * 8]);
#pragma unroll
    for (int mt = 0; mt < 2; mt++)
#pragma unroll
      for (int nt = 0; nt < 4; nt++)
        acc[mt][nt] = MFMA32(af[mt], bfr[nt], acc[mt][nt]);
  };

  stage(0, 0);
  for (int k0 = 0; k0 < K; k0 += 64) {
    __syncthreads();
    if (k0 + 32 < K) stage(k0 + 32, 1);
    compute(0);
    __syncthreads();
    if (k0 + 64 < K) stage(k0 + 64, 0);
    compute(1);
  }

#pragma unroll
  for (int mt = 0; mt < 2; mt++) {
#pragma unroll
    for (int nt = 0; nt < 4; nt++) {
      const int col = n0 + wn + nt * 16 + l16;
      const int row = m0 + wm + mt * 16 + quad * 4;
#pragma unroll
      for (int r = 0; r < 4; r++)
        C[(size_t)(row + r) * N + col] = (TC)acc[mt][nt][r];
    }
  }
}

// Fused K+V projection, split-K x8. A = xb (bf16), B = Wk/Wv (f32 -> bf16).
__global__ __launch_bounds__(256) void kv_gemm(const bf16* __restrict__ xb,
                                               const float* __restrict__ Wk,
                                               const float* __restrict__ Wv,
                                               float* __restrict__ Kf,
                                               float* __restrict__ Vf) {
  __shared__ __align__(16) bf16 As[128 * 40];
  __shared__ __align__(16) bf16 Bs[128 * 40];
  const int tid = threadIdx.x;
  const int wave = tid >> 6, lane = tid & 63;
  const int quad = lane >> 4, l16 = lane & 15;
  const int m0 = blockIdx.y * 128;
  const int kbeg = blockIdx.x * 256, kend = kbeg + 256;
  const int wm = (wave >> 1) * 64, wn = (wave & 1) * 64;

  floatx4 acc[4][4];
#pragma unroll
  for (int i = 0; i < 4; i++)
#pragma unroll
    for (int j = 0; j < 4; j++) acc[i][j] = (floatx4)0.f;

  const int sr = tid >> 2, sc = (tid & 3) * 8;

  for (int k0 = kbeg; k0 < kend; k0 += 32) {
    __syncthreads();
#pragma unroll
    for (int rr = 0; rr < 2; rr++) {
      const int row = sr + rr * 64;
      *(bf16x8*)(&As[row * 40 + sc]) =
          *(const bf16x8*)(&xb[(size_t)(m0 + row) * 2048 + k0 + sc]);
      const float* bsrc = (row < 64) ? &Wk[(size_t)row * 2048 + k0 + sc]
                                     : &Wv[(size_t)(row - 64) * 2048 + k0 + sc];
      *(bf16x8*)(&Bs[row * 40 + sc]) = load8(bsrc);
    }
    __syncthreads();

    bf16x8 af[4], bfr[4];
#pragma unroll
    for (int mt = 0; mt < 4; mt++)
      af[mt] = *(const bf16x8*)(&As[(wm + mt * 16 + l16) * 40 + quad * 8]);
#pragma unroll
    for (int nt = 0; nt < 4; nt++)
      bfr[nt] = *(const bf16x8*)(&Bs[(wn + nt * 16 + l16) * 40 + quad * 8]);
#pragma unroll
    for (int mt = 0; mt < 4; mt++)
#pragma unroll
      for (int nt = 0; nt < 4; nt++)
        acc[mt][nt] = MFMA32(af[mt], bfr[nt], acc[mt][nt]);
  }

#pragma unroll
  for (int mt = 0; mt < 4; mt++) {
#pragma unroll
    for (int nt = 0; nt < 4; nt++) {
      const int col = wn + nt * 16 + l16;
      const int row = m0 + wm + mt * 16 + quad * 4;
      float* dst = (col < 64) ? &Kf[(size_t)row * 64 + col]
                              : &Vf[(size_t)row * 64 + (col - 64)];
#pragma unroll
      for (int r = 0; r < 4; r++) atomicAdd(dst + (size_t)r * 64, acc[mt][nt][r]);
    }
  }
}

// Flash attention, S^T orientation, max-free softmax.
// R8 structure: 1024 threads = 16 waves = 2 k-split groups of 8 q-row waves
// over the same 128-row q-tile. Group g computes keys [lo+g*n, ...) with its
// own double-buffered XOR-swizzled LDS tiles; partials (sum PV, sum l) are
// plain-additive (max-free) and merged through LDS at the end. 512 blocks x
// 32 waves -> 2 blocks/CU = 32 waves/CU (VGPR<=64 via launch_bounds).
// ALiBi window: tile dropped when slope2*(qw0-k0-63) > 44 -> dropped terms
// < 2^-26 of the kept on-diagonal term (score spread |s|*scale2 <= ~9).
// Block-level lower bound lo_t prunes the staging loop itself.
__global__ __launch_bounds__(1024, 8) void attn_kernel(const bf16* __restrict__ Q,
                                                       const bf16* __restrict__ Kb,
                                                       const bf16* __restrict__ Vtb,
                                                       bf16* __restrict__ O) {
  __shared__ __align__(16) char smem[65536];
  bf16* const Ksm = (bf16*)smem;            // [grp*2+buf][64*64] key-major, swz
  bf16* const Vsm = (bf16*)(smem + 32768);  // [grp*2+buf][64*64] = [d][key], swz
  float* const comb = (float*)smem;         // epilogue alias [8*64][17]

  const int tid = threadIdx.x;
  const int wq = tid >> 6;    // 0..15
  const int grp = wq >> 3;    // k-split group
  const int wrow = wq & 7;    // q-row wave within group
  const int lane = tid & 63;
  const int quad = lane >> 4, l16 = lane & 15;
  const int h = blockIdx.y;
  const int t = (blockIdx.y < 16) ? (15 - blockIdx.x) : blockIdx.x;  // q-tile
  const float scale2 = 0.125f * 1.44269504f;
  const float slope2 = exp2f(-0.25f * (float)(h + 1)) * 1.44269504f;

  float cq[4];
#pragma unroll
  for (int r = 0; r < 4; r++) cq[r] = slope2 * (float)(quad * 4 + r);
  const float s16 = slope2 * 16.f;
  const bf16x4 ones = {(bf16)1.f, (bf16)1.f, (bf16)1.f, (bf16)1.f};

  const int qi = t * 128 + wrow * 16 + l16;  // this lane's query row
  bf16x8 qf[2];
#pragma unroll
  for (int kk = 0; kk < 2; kk++)
    qf[kk] = *(const bf16x8*)(&Q[(size_t)qi * 2048 + h * 64 + kk * 32 + quad * 8]);

  floatx4 oacc[4];
#pragma unroll
  for (int dt = 0; dt < 4; dt++) oacc[dt] = (floatx4)0.f;
  floatx4 lacc = (floatx4)0.f;

  // k-range for this block/group (64-key tiles): [lo_t, end) split in half.
  const int end = 2 * t + 2;
  const int lo_key = t * 128 - (int)(44.f / slope2);
  const int lo_t = (lo_key <= 0) ? 0 : (lo_key >> 6);
  const int n = (end - lo_t + 1) >> 1;  // iterations per group (block-uniform)
  const int base = lo_t + grp * n;
  const int kt_last = end - 1;
  const int qw0 = t * 128 + wrow * 16;  // wave's min q

  // staging: each group's 512 threads stage its own 64x64 K and V tiles
  const int tg = tid & 511;
  const int r0 = tg >> 3, sl = tg & 7;        // row 0..63, 16B slot 0..7
  const int wsw = ((sl ^ (r0 & 7)) << 3);     // XOR-swizzled elem offset
  const int sx = l16 & 7;                     // read-side swizzle bits

  int kn = min(base, kt_last) * 64;
  bf16x8 kreg = *(const bf16x8*)(&Kb[(size_t)(kn + r0) * 64 + sl * 8]);
  bf16x8 vreg = *(const bf16x8*)(&Vtb[(size_t)r0 * 2048 + kn + sl * 8]);

  for (int i = 0; i < n; i++) {
    const int kt = base + i;
    const int bofs = (grp * 2 + (i & 1)) * 4096;
    // write own buf: prev tile (buf^1) may still be computing - different buf.
    // This buf's old data (i-2) was fully read before barrier(i-1).
    *(bf16x8*)(&Ksm[bofs + r0 * 64 + wsw]) = kreg;
    *(bf16x8*)(&Vsm[bofs + r0 * 64 + wsw]) = vreg;
    __syncthreads();  // tile kt visible (both groups)
    if (i + 1 < n) {  // prefetch next tile (clamped for grp1 dummy tail)
      const int kn2 = min(kt + 1, kt_last) * 64;
      kreg = *(const bf16x8*)(&Kb[(size_t)(kn2 + r0) * 64 + sl * 8]);
      vreg = *(const bf16x8*)(&Vtb[(size_t)r0 * 2048 + kn2 + sl * 8]);
    }
    const int k0 = kt * 64;
    if (kt >= end) continue;                                  // odd-R dummy
    if (k0 > qw0 + 15) continue;                              // causal skip
    if ((float)(qw0 - k0 - 63) * slope2 > 44.f) continue;     // ALiBi window

    const bf16* ks = Ksm + bofs;
    const bf16* vs = Vsm + bofs;

    // S^T[key][q] = K . Q^T
    floatx4 s[4];
#pragma unroll
    for (int mt = 0; mt < 4; mt++) s[mt] = (floatx4)0.f;
#pragma unroll
    for (int kk = 0; kk < 2; kk++) {
#pragma unroll
      for (int mt = 0; mt < 4; mt++) {
        bf16x8 kf = *(const bf16x8*)(
            &ks[(mt * 16 + l16) * 64 + (((kk * 4 + quad) ^ sx) << 3)]);
        s[mt] = MFMA32(kf, qf[kk], s[mt]);
      }
    }

    // p = exp2(s*scale2 + slope2*(j-i)); scores bounded -> no running max
    const float base0 = slope2 * (float)(k0 - qi);
    bf16x4 pb[4];
    if (k0 + 63 <= qw0) {  // interior for the whole wave: no mask
      float b = base0;
#pragma unroll
      for (int mt = 0; mt < 4; mt++) {
        bf16x4 tb;
#pragma unroll
        for (int r = 0; r < 4; r++)
          tb[r] = (bf16)exp2f(__builtin_fmaf(s[mt][r], scale2, b + cq[r]));
        pb[mt] = tb;
        b += s16;
      }
    } else {  // diagonal tile: per-lane causal mask
      const int qloc = qi - k0;
      float b = base0;
#pragma unroll
      for (int mt = 0; mt < 4; mt++) {
        bf16x4 tb;
#pragma unroll
        for (int r = 0; r < 4; r++) {
          const int moff = mt * 16 + quad * 4 + r;
          const float p = exp2f(__builtin_fmaf(s[mt][r], scale2, b + cq[r]));
          tb[r] = (moff <= qloc) ? (bf16)p : (bf16)0.f;
        }
        pb[mt] = tb;
        b += s16;
      }
    }

    // O^T[d][q] += V^T . P^T ; l += 1 . P^T (matrix-pipe row-sum)
#pragma unroll
    for (int mt = 0; mt < 4; mt++) {
      lacc = mfma16(ones, pb[mt], lacc);
#pragma unroll
      for (int dt = 0; dt < 4; dt++) {
        const int slot = 2 * mt + (quad >> 1);
        const bf16x4 va = *(const bf16x4*)(
            &vs[(dt * 16 + l16) * 64 + ((slot ^ sx) << 3) + (quad & 1) * 4]);
        oacc[dt] = mfma16(va, pb[mt], oacc[dt]);
      }
    }
  }

  // merge the two k-halves through LDS (plain sums: max-free softmax)
  __syncthreads();
  if (grp == 1) {
    float* c = comb + (size_t)(wrow * 64 + lane) * 17;
#pragma unroll
    for (int dt = 0; dt < 4; dt++)
#pragma unroll
      for (int r = 0; r < 4; r++) c[dt * 4 + r] = oacc[dt][r];
    c[16] = lacc[0];
  }
  __syncthreads();
  if (grp == 0) {
    const float* c = comb + (size_t)(wrow * 64 + lane) * 17;
    const float linv = 1.0f / (lacc[0] + c[16]);
#pragma unroll
    for (int dt = 0; dt < 4; dt++) {
      bf16x4 ob;
#pragma unroll
      for (int r = 0; r < 4; r++)
        ob[r] = (bf16)((oacc[dt][r] + c[dt * 4 + r]) * linv);
      *(bf16x4*)(&O[(size_t)qi * 2048 + h * 64 + dt * 16 + quad * 4]) = ob;
    }
  }
}

extern "C" void kernel_launch(void* const* d_in, const int* in_sizes, int n_in,
                              void* d_out, int out_size, void* d_ws,
                              size_t ws_size, hipStream_t stream) {
  (void)in_sizes; (void)n_in; (void)out_size; (void)ws_size;
  const float* x = (const float*)d_in[0];
  const float* Wq = (const float*)d_in[1];
  const float* Wk = (const float*)d_in[2];
  const float* Wv = (const float*)d_in[3];
  const float* Wo = (const float*)d_in[4];
  float* out = (float*)d_out;

  const size_t NE = (size_t)2048 * 2048;
  bf16* xb = (bf16*)d_ws;              // 8 MB (reused as AO after Q-proj)
  bf16* Wqb = xb + NE;                 // 8 MB
  bf16* Wob = Wqb + NE;                // 8 MB
  bf16* Qb = Wob + NE;                 // 8 MB
  float* Kf = (float*)(Qb + NE);       // 512 KB
  float* Vf = Kf + 2048 * 64;          // 512 KB
  bf16* Kb = (bf16*)(Vf + 2048 * 64);  // 256 KB
  bf16* Vtb = Kb + 2048 * 64;          // 256 KB
  bf16* AO = xb;

  hipMemsetAsync(Kf, 0, 2 * 2048 * 64 * sizeof(float), stream);
  conv3<<<dim3(2048, 3), 256, 0, stream>>>(x, xb, Wq, Wqb, Wo, Wob);
  gemm_bt_a<bf16><<<dim3(16, 32), 256, 0, stream>>>(xb, Wqb, Qb, 2048, 2048, 2048);
  kv_gemm<<<dim3(8, 16), 256, 0, stream>>>(xb, Wk, Wv, Kf, Vf);
  pack_kv<<<512, 256, 0, stream>>>(Kf, Vf, Kb, Vtb);
  attn_kernel<<<dim3(16, 32), 1024, 0, stream>>>(Qb, Kb, Vtb, AO);
  gemm_bt_a<float><<<dim3(16, 32), 256, 0, stream>>>(AO, Wob, out, 2048, 2048, 2048);
}

// Round 2
// 246.123 us; speedup vs baseline: 1.2188x; 1.2188x over previous
//
#include <hip/hip_runtime.h>
#include <stdint.h>

typedef __bf16 bf16;
typedef __bf16 bf16x4 __attribute__((ext_vector_type(4)));
typedef __bf16 bf16x8 __attribute__((ext_vector_type(8)));
typedef short short4v __attribute__((ext_vector_type(4)));
typedef float floatx4 __attribute__((ext_vector_type(4)));

#define MFMA32(a, b, c) __builtin_amdgcn_mfma_f32_16x16x32_bf16((a), (b), (c), 0, 0, 0)

__device__ __forceinline__ floatx4 mfma16(bf16x4 a, bf16x4 b, floatx4 c) {
  return __builtin_amdgcn_mfma_f32_16x16x16bf16_1k(
      __builtin_bit_cast(short4v, a), __builtin_bit_cast(short4v, b), c, 0, 0, 0);
}

__device__ __forceinline__ void gload16(const void* g, void* l) {
  __builtin_amdgcn_global_load_lds(
      (const __attribute__((address_space(1))) void*)g,
      (__attribute__((address_space(3))) void*)l, 16, 0, 0);
}

__device__ __forceinline__ bf16x8 load8(const float* p) {
  float4 lo = *(const float4*)p;
  float4 hi = *(const float4*)(p + 4);
  bf16x8 r;
  r[0] = (bf16)lo.x; r[1] = (bf16)lo.y; r[2] = (bf16)lo.z; r[3] = (bf16)lo.w;
  r[4] = (bf16)hi.x; r[5] = (bf16)hi.y; r[6] = (bf16)hi.z; r[7] = (bf16)hi.w;
  return r;
}

// One launch converting x, Wq, Wo to bf16. grid (2048, 3), 8 elems/thread.
__global__ __launch_bounds__(256) void conv3(const float* __restrict__ a, bf16* __restrict__ ab,
                                             const float* __restrict__ b, bf16* __restrict__ bb,
                                             const float* __restrict__ c, bf16* __restrict__ cb) {
  const int i = blockIdx.x * 256 + threadIdx.x;
  const float* src = blockIdx.y == 0 ? a : (blockIdx.y == 1 ? b : c);
  bf16* dst = blockIdx.y == 0 ? ab : (blockIdx.y == 1 ? bb : cb);
  ((bf16x8*)dst)[i] = load8(src + (size_t)i * 8);
}

// Pack K (f32->bf16) and transpose-pack V: Vf[t][64] -> Vtb[d][2048].
__global__ __launch_bounds__(256) void pack_kv(const float* __restrict__ Kf,
                                               const float* __restrict__ Vf,
                                               bf16* __restrict__ Kb,
                                               bf16* __restrict__ Vtb) {
  int i = blockIdx.x * 256 + threadIdx.x;
  if (i < 2048 * 64) {
    Kb[i] = (bf16)Kf[i];
    const int t = i >> 6, d = i & 63;
    Vtb[(size_t)d * 2048 + t] = (bf16)Vf[i];
  }
}

// C[M,N] = A[M,K] @ B[N,K]^T, bf16 in, dbuf global_load_lds staging.
// 64x128 C-tile -> 512 blocks = 2 blocks/CU co-resident (R6 validated).
template <typename TC>
__global__ __launch_bounds__(256) void gemm_bt_a(const bf16* __restrict__ A,
                                                 const bf16* __restrict__ B,
                                                 TC* __restrict__ C,
                                                 int M, int N, int K) {
  __shared__ __align__(16) bf16 As[2][64 * 32];
  __shared__ __align__(16) bf16 Bs[2][128 * 32];
  const int tid = threadIdx.x;
  const int wave = tid >> 6, lane = tid & 63;
  const int quad = lane >> 4, l16 = lane & 15;
  const int m0 = blockIdx.y * 64, n0 = blockIdx.x * 128;
  const int wm = (wave >> 1) * 32, wn = (wave & 1) * 64;

  floatx4 acc[2][4];
#pragma unroll
  for (int i = 0; i < 2; i++)
#pragma unroll
    for (int j = 0; j < 4; j++) acc[i][j] = (floatx4)0.f;

  const int srow = tid >> 2, scol = (tid & 3) * 8;
  const bf16* Ap = A + (size_t)(m0 + srow) * K + scol;
  const bf16* Bp = B + (size_t)(n0 + srow) * K + scol;

  auto stage = [&](int k0, int buf) {
    gload16(Ap + k0, (char*)As[buf] + tid * 16);
    gload16(Bp + k0, (char*)Bs[buf] + tid * 16);
    gload16(Bp + (size_t)64 * K + k0, (char*)Bs[buf] + 4096 + tid * 16);
  };
  auto compute = [&](int buf) {
    bf16x8 af[2], bfr[4];
#pragma unroll
    for (int mt = 0; mt < 2; mt++)
      af[mt] = *(const bf16x8*)(&As[buf][(wm + mt * 16 + l16) * 32 + quad * 8]);
#pragma unroll
    for (int nt = 0; nt < 4; nt++)
      bfr[nt] = *(const bf16x8*)(&Bs[buf][(wn + nt * 16 + l16) * 32 + quad * 8]);
#pragma unroll
    for (int mt = 0; mt < 2; mt++)
#pragma unroll
      for (int nt = 0; nt < 4; nt++)
        acc[mt][nt] = MFMA32(af[mt], bfr[nt], acc[mt][nt]);
  };

  stage(0, 0);
  for (int k0 = 0; k0 < K; k0 += 64) {
    __syncthreads();
    if (k0 + 32 < K) stage(k0 + 32, 1);
    compute(0);
    __syncthreads();
    if (k0 + 64 < K) stage(k0 + 64, 0);
    compute(1);
  }

#pragma unroll
  for (int mt = 0; mt < 2; mt++) {
#pragma unroll
    for (int nt = 0; nt < 4; nt++) {
      const int col = n0 + wn + nt * 16 + l16;
      const int row = m0 + wm + mt * 16 + quad * 4;
#pragma unroll
      for (int r = 0; r < 4; r++)
        C[(size_t)(row + r) * N + col] = (TC)acc[mt][nt][r];
    }
  }
}

// Fused K+V projection, split-K x8. A = xb (bf16), B = Wk/Wv (f32 -> bf16).
__global__ __launch_bounds__(256) void kv_gemm(const bf16* __restrict__ xb,
                                               const float* __restrict__ Wk,
                                               const float* __restrict__ Wv,
                                               float* __restrict__ Kf,
                                               float* __restrict__ Vf) {
  __shared__ __align__(16) bf16 As[128 * 40];
  __shared__ __align__(16) bf16 Bs[128 * 40];
  const int tid = threadIdx.x;
  const int wave = tid >> 6, lane = tid & 63;
  const int quad = lane >> 4, l16 = lane & 15;
  const int m0 = blockIdx.y * 128;
  const int kbeg = blockIdx.x * 256, kend = kbeg + 256;
  const int wm = (wave >> 1) * 64, wn = (wave & 1) * 64;

  floatx4 acc[4][4];
#pragma unroll
  for (int i = 0; i < 4; i++)
#pragma unroll
    for (int j = 0; j < 4; j++) acc[i][j] = (floatx4)0.f;

  const int sr = tid >> 2, sc = (tid & 3) * 8;

  for (int k0 = kbeg; k0 < kend; k0 += 32) {
    __syncthreads();
#pragma unroll
    for (int rr = 0; rr < 2; rr++) {
      const int row = sr + rr * 64;
      *(bf16x8*)(&As[row * 40 + sc]) =
          *(const bf16x8*)(&xb[(size_t)(m0 + row) * 2048 + k0 + sc]);
      const float* bsrc = (row < 64) ? &Wk[(size_t)row * 2048 + k0 + sc]
                                     : &Wv[(size_t)(row - 64) * 2048 + k0 + sc];
      *(bf16x8*)(&Bs[row * 40 + sc]) = load8(bsrc);
    }
    __syncthreads();

    bf16x8 af[4], bfr[4];
#pragma unroll
    for (int mt = 0; mt < 4; mt++)
      af[mt] = *(const bf16x8*)(&As[(wm + mt * 16 + l16) * 40 + quad * 8]);
#pragma unroll
    for (int nt = 0; nt < 4; nt++)
      bfr[nt] = *(const bf16x8*)(&Bs[(wn + nt * 16 + l16) * 40 + quad * 8]);
#pragma unroll
    for (int mt = 0; mt < 4; mt++)
#pragma unroll
      for (int nt = 0; nt < 4; nt++)
        acc[mt][nt] = MFMA32(af[mt], bfr[nt], acc[mt][nt]);
  }

#pragma unroll
  for (int mt = 0; mt < 4; mt++) {
#pragma unroll
    for (int nt = 0; nt < 4; nt++) {
      const int col = wn + nt * 16 + l16;
      const int row = m0 + wm + mt * 16 + quad * 4;
      float* dst = (col < 64) ? &Kf[(size_t)row * 64 + col]
                              : &Vf[(size_t)row * 64 + (col - 64)];
#pragma unroll
      for (int r = 0; r < 4; r++) atomicAdd(dst + (size_t)r * 64, acc[mt][nt][r]);
    }
  }
}

// Flash attention, S^T orientation, max-free softmax.
// Structure: 1024 threads = 16 waves = 2 k-split groups of 8 q-row waves
// over the same 128-row q-tile. Group g computes half the (windowed) key
// range with its own double-buffered XOR-swizzled LDS tiles; partials
// (sum PV, sum l) are plain-additive (max-free) and merged through LDS.
// NOTE: plain __launch_bounds__(1024) — the forced (1024,8) variant capped
// the allocator below the ~60-VGPR live set and spilled ~180MB/dispatch to
// scratch (R1: VGPR=32, FETCH 85MB, 103us). Natural allocation is ~56-64:
// <=64 -> 2 blocks/CU = 32 waves/CU; worst case 1 block/CU = 16 waves.
// ALiBi window: tile dropped when slope2*(qw0-k0-63) > 44 -> dropped terms
// < 2^-26 of the kept on-diagonal term (score spread |s|*scale2 <= ~9).
__global__ __launch_bounds__(1024) void attn_kernel(const bf16* __restrict__ Q,
                                                    const bf16* __restrict__ Kb,
                                                    const bf16* __restrict__ Vtb,
                                                    bf16* __restrict__ O) {
  __shared__ __align__(16) char smem[65536];
  bf16* const Ksm = (bf16*)smem;            // [grp*2+buf][64*64] key-major, swz
  bf16* const Vsm = (bf16*)(smem + 32768);  // [grp*2+buf][64*64] = [d][key], swz
  float* const comb = (float*)smem;         // epilogue alias [8*64][17]

  const int tid = threadIdx.x;
  const int wq = tid >> 6;    // 0..15
  const int grp = wq >> 3;    // k-split group
  const int wrow = wq & 7;    // q-row wave within group
  const int lane = tid & 63;
  const int quad = lane >> 4, l16 = lane & 15;
  const int h = blockIdx.y;
  const int t = (blockIdx.y < 16) ? (15 - blockIdx.x) : blockIdx.x;  // q-tile
  const float scale2 = 0.125f * 1.44269504f;
  const float slope2 = exp2f(-0.25f * (float)(h + 1)) * 1.44269504f;

  float cq[4];
#pragma unroll
  for (int r = 0; r < 4; r++) cq[r] = slope2 * (float)(quad * 4 + r);
  const float s16 = slope2 * 16.f;
  const bf16x4 ones = {(bf16)1.f, (bf16)1.f, (bf16)1.f, (bf16)1.f};

  const int qi = t * 128 + wrow * 16 + l16;  // this lane's query row
  bf16x8 qf[2];
#pragma unroll
  for (int kk = 0; kk < 2; kk++)
    qf[kk] = *(const bf16x8*)(&Q[(size_t)qi * 2048 + h * 64 + kk * 32 + quad * 8]);

  floatx4 oacc[4];
#pragma unroll
  for (int dt = 0; dt < 4; dt++) oacc[dt] = (floatx4)0.f;
  floatx4 lacc = (floatx4)0.f;

  // k-range for this block/group (64-key tiles): [lo_t, end) split in half.
  const int end = 2 * t + 2;
  const int lo_key = t * 128 - (int)(44.f / slope2);
  const int lo_t = (lo_key <= 0) ? 0 : (lo_key >> 6);
  const int n = (end - lo_t + 1) >> 1;  // iterations per group (block-uniform)
  const int base = lo_t + grp * n;
  const int kt_last = end - 1;
  const int qw0 = t * 128 + wrow * 16;  // wave's min q

  // staging: each group's 512 threads stage its own 64x64 K and V tiles
  const int tg = tid & 511;
  const int r0 = tg >> 3, sl = tg & 7;        // row 0..63, 16B slot 0..7
  const int wsw = ((sl ^ (r0 & 7)) << 3);     // XOR-swizzled elem offset
  const int sx = l16 & 7;                     // read-side swizzle bits

  int kn = min(base, kt_last) * 64;
  bf16x8 kreg = *(const bf16x8*)(&Kb[(size_t)(kn + r0) * 64 + sl * 8]);
  bf16x8 vreg = *(const bf16x8*)(&Vtb[(size_t)r0 * 2048 + kn + sl * 8]);

  for (int i = 0; i < n; i++) {
    const int kt = base + i;
    const int bofs = (grp * 2 + (i & 1)) * 4096;
    // write own buf: prev tile (buf^1) may still be computing - different buf.
    // This buf's old data (i-2) was fully read before barrier(i-1).
    *(bf16x8*)(&Ksm[bofs + r0 * 64 + wsw]) = kreg;
    *(bf16x8*)(&Vsm[bofs + r0 * 64 + wsw]) = vreg;
    __syncthreads();  // tile kt visible (both groups)
    if (i + 1 < n) {  // prefetch next tile (clamped for grp1 dummy tail)
      const int kn2 = min(kt + 1, kt_last) * 64;
      kreg = *(const bf16x8*)(&Kb[(size_t)(kn2 + r0) * 64 + sl * 8]);
      vreg = *(const bf16x8*)(&Vtb[(size_t)r0 * 2048 + kn2 + sl * 8]);
    }
    const int k0 = kt * 64;
    if (kt >= end) continue;                                  // odd-R dummy
    if (k0 > qw0 + 15) continue;                              // causal skip
    if ((float)(qw0 - k0 - 63) * slope2 > 44.f) continue;     // ALiBi window

    const bf16* ks = Ksm + bofs;
    const bf16* vs = Vsm + bofs;

    // S^T[key][q] = K . Q^T
    floatx4 s[4];
#pragma unroll
    for (int mt = 0; mt < 4; mt++) s[mt] = (floatx4)0.f;
#pragma unroll
    for (int kk = 0; kk < 2; kk++) {
#pragma unroll
      for (int mt = 0; mt < 4; mt++) {
        bf16x8 kf = *(const bf16x8*)(
            &ks[(mt * 16 + l16) * 64 + (((kk * 4 + quad) ^ sx) << 3)]);
        s[mt] = MFMA32(kf, qf[kk], s[mt]);
      }
    }

    // p = exp2(s*scale2 + slope2*(j-i)); scores bounded -> no running max
    const float base0 = slope2 * (float)(k0 - qi);
    bf16x4 pb[4];
    if (k0 + 63 <= qw0) {  // interior for the whole wave: no mask
      float b = base0;
#pragma unroll
      for (int mt = 0; mt < 4; mt++) {
        bf16x4 tb;
#pragma unroll
        for (int r = 0; r < 4; r++)
          tb[r] = (bf16)exp2f(__builtin_fmaf(s[mt][r], scale2, b + cq[r]));
        pb[mt] = tb;
        b += s16;
      }
    } else {  // diagonal tile: per-lane causal mask
      const int qloc = qi - k0;
      float b = base0;
#pragma unroll
      for (int mt = 0; mt < 4; mt++) {
        bf16x4 tb;
#pragma unroll
        for (int r = 0; r < 4; r++) {
          const int moff = mt * 16 + quad * 4 + r;
          const float p = exp2f(__builtin_fmaf(s[mt][r], scale2, b + cq[r]));
          tb[r] = (moff <= qloc) ? (bf16)p : (bf16)0.f;
        }
        pb[mt] = tb;
        b += s16;
      }
    }

    // O^T[d][q] += V^T . P^T ; l += 1 . P^T (matrix-pipe row-sum)
#pragma unroll
    for (int mt = 0; mt < 4; mt++) {
      lacc = mfma16(ones, pb[mt], lacc);
#pragma unroll
      for (int dt = 0; dt < 4; dt++) {
        const int slot = 2 * mt + (quad >> 1);
        const bf16x4 va = *(const bf16x4*)(
            &vs[(dt * 16 + l16) * 64 + ((slot ^ sx) << 3) + (quad & 1) * 4]);
        oacc[dt] = mfma16(va, pb[mt], oacc[dt]);
      }
    }
  }

  // merge the two k-halves through LDS (plain sums: max-free softmax)
  __syncthreads();
  if (grp == 1) {
    float* c = comb + (size_t)(wrow * 64 + lane) * 17;
#pragma unroll
    for (int dt = 0; dt < 4; dt++)
#pragma unroll
      for (int r = 0; r < 4; r++) c[dt * 4 + r] = oacc[dt][r];
    c[16] = lacc[0];
  }
  __syncthreads();
  if (grp == 0) {
    const float* c = comb + (size_t)(wrow * 64 + lane) * 17;
    const float linv = 1.0f / (lacc[0] + c[16]);
#pragma unroll
    for (int dt = 0; dt < 4; dt++) {
      bf16x4 ob;
#pragma unroll
      for (int r = 0; r < 4; r++)
        ob[r] = (bf16)((oacc[dt][r] + c[dt * 4 + r]) * linv);
      *(bf16x4*)(&O[(size_t)qi * 2048 + h * 64 + dt * 16 + quad * 4]) = ob;
    }
  }
}

extern "C" void kernel_launch(void* const* d_in, const int* in_sizes, int n_in,
                              void* d_out, int out_size, void* d_ws,
                              size_t ws_size, hipStream_t stream) {
  (void)in_sizes; (void)n_in; (void)out_size; (void)ws_size;
  const float* x = (const float*)d_in[0];
  const float* Wq = (const float*)d_in[1];
  const float* Wk = (const float*)d_in[2];
  const float* Wv = (const float*)d_in[3];
  const float* Wo = (const float*)d_in[4];
  float* out = (float*)d_out;

  const size_t NE = (size_t)2048 * 2048;
  bf16* xb = (bf16*)d_ws;              // 8 MB (reused as AO after Q-proj)
  bf16* Wqb = xb + NE;                 // 8 MB
  bf16* Wob = Wqb + NE;                // 8 MB
  bf16* Qb = Wob + NE;                 // 8 MB
  float* Kf = (float*)(Qb + NE);       // 512 KB
  float* Vf = Kf + 2048 * 64;          // 512 KB
  bf16* Kb = (bf16*)(Vf + 2048 * 64);  // 256 KB
  bf16* Vtb = Kb + 2048 * 64;          // 256 KB
  bf16* AO = xb;

  hipMemsetAsync(Kf, 0, 2 * 2048 * 64 * sizeof(float), stream);
  conv3<<<dim3(2048, 3), 256, 0, stream>>>(x, xb, Wq, Wqb, Wo, Wob);
  gemm_bt_a<bf16><<<dim3(16, 32), 256, 0, stream>>>(xb, Wqb, Qb, 2048, 2048, 2048);
  kv_gemm<<<dim3(8, 16), 256, 0, stream>>>(xb, Wk, Wv, Kf, Vf);
  pack_kv<<<512, 256, 0, stream>>>(Kf, Vf, Kb, Vtb);
  attn_kernel<<<dim3(16, 32), 1024, 0, stream>>>(Qb, Kb, Vtb, AO);
  gemm_bt_a<float><<<dim3(16, 32), 256, 0, stream>>>(AO, Wob, out, 2048, 2048, 2048);
}